// Round 1
// baseline (3191.763 us; speedup 1.0000x reference)
//
#include <hip/hip_runtime.h>
#include <hip/hip_bf16.h>
#include <cstddef>

// GNN: dense1+BN+ReLU -> SAGE(mean) -> dense2+BN+ReLU -> SAGE(mean) -> dense_out
// Round 0: fp32 correctness-first baseline.
//   - gemm_k128: C = act(A1@W1^T [+ A2@W2^T] + b), K=128 fixed, tiled 64xNC,
//     256 thr, 4x(NC/64)x4 acc/thread, LDS k-major staging (padded strides).
//     In-place safe: C row m depends only on A row m; each block writes only
//     its own rows, in the epilogue, after all K chunks are consumed.
//   - aggregation: fp32 atomicAdd scatter (avg deg = 8, low contention).
//   - BN: column stats via per-block partials + atomic combine, then fused
//     scale/shift+relu elementwise.

#define NN 100000
#define NE 800000

// ---------------- graph kernels ----------------

__global__ __launch_bounds__(256) void deg_kernel(const int* __restrict__ dst, float* deg, int E) {
    int e = blockIdx.x * 256 + threadIdx.x;
    if (e < E) atomicAdd(&deg[dst[e]], 1.0f);
}

__global__ __launch_bounds__(256) void invdeg_kernel(const float* __restrict__ deg, float* invdeg, int n) {
    int i = blockIdx.x * 256 + threadIdx.x;
    if (i < n) invdeg[i] = 1.0f / fmaxf(deg[i], 1.0f);
}

// one edge handled by 32 threads (4 floats each)
__global__ __launch_bounds__(256) void scatter_kernel(const float* __restrict__ X, const int* __restrict__ src,
                                                      const int* __restrict__ dst, float* agg, int E) {
    int gid = blockIdx.x * 256 + threadIdx.x;
    int e = gid >> 5;
    if (e >= E) return;
    int c = (gid & 31) * 4;
    int s = src[e], d = dst[e];
    const float4 v = *(const float4*)&X[(size_t)s * 128 + c];
    float* p = &agg[(size_t)d * 128 + c];
    atomicAdd(p + 0, v.x);
    atomicAdd(p + 1, v.y);
    atomicAdd(p + 2, v.z);
    atomicAdd(p + 3, v.w);
}

__global__ __launch_bounds__(256) void meanscale_kernel(float* agg, const float* __restrict__ invdeg, int n4) {
    int gid = blockIdx.x * 256 + threadIdx.x;
    if (gid >= n4) return;
    float iv = invdeg[gid >> 5];
    float4* p = (float4*)agg + gid;
    float4 v = *p;
    v.x *= iv; v.y *= iv; v.z *= iv; v.w *= iv;
    *p = v;
}

// ---------------- batchnorm ----------------

__global__ __launch_bounds__(256) void colstats_kernel(const float* __restrict__ X, int M, float* stats) {
    __shared__ float sred[8][128];
    __shared__ float qred[8][128];
    int tid = threadIdx.x;
    int cg = (tid & 31) * 4;  // column (float) base
    int rl = tid >> 5;        // row lane 0..7
    float sx = 0, sy = 0, sz = 0, sw = 0, qx = 0, qy = 0, qz = 0, qw = 0;
    for (int r = blockIdx.x * 8 + rl; r < M; r += gridDim.x * 8) {
        float4 v = *(const float4*)&X[(size_t)r * 128 + cg];
        sx += v.x; sy += v.y; sz += v.z; sw += v.w;
        qx += v.x * v.x; qy += v.y * v.y; qz += v.z * v.z; qw += v.w * v.w;
    }
    sred[rl][cg + 0] = sx; sred[rl][cg + 1] = sy; sred[rl][cg + 2] = sz; sred[rl][cg + 3] = sw;
    qred[rl][cg + 0] = qx; qred[rl][cg + 1] = qy; qred[rl][cg + 2] = qz; qred[rl][cg + 3] = qw;
    __syncthreads();
    if (tid < 128) {
        float s = 0, q = 0;
#pragma unroll
        for (int r = 0; r < 8; r++) { s += sred[r][tid]; q += qred[r][tid]; }
        atomicAdd(&stats[tid], s);
        atomicAdd(&stats[128 + tid], q);
    }
}

__global__ void bn_finalize_kernel(const float* __restrict__ stats, const float* __restrict__ gamma,
                                   const float* __restrict__ beta, float* bnp, float invM) {
    int c = threadIdx.x;  // 128 threads
    float mean = stats[c] * invM;
    float var = stats[128 + c] * invM - mean * mean;
    float sc = gamma[c] * rsqrtf(var + 1e-5f);
    bnp[c] = sc;
    bnp[128 + c] = beta[c] - mean * sc;
}

__global__ __launch_bounds__(256) void bn_relu_kernel(float* X, const float* __restrict__ bnp, int n4) {
    int gid = blockIdx.x * 256 + threadIdx.x;
    if (gid >= n4) return;
    int c = (gid & 31) * 4;
    float4 s = *(const float4*)&bnp[c];
    float4 t = *(const float4*)&bnp[128 + c];
    float4* p = (float4*)X + gid;
    float4 v = *p;
    v.x = fmaxf(fmaf(v.x, s.x, t.x), 0.f);
    v.y = fmaxf(fmaf(v.y, s.y, t.y), 0.f);
    v.z = fmaxf(fmaf(v.z, s.z, t.z), 0.f);
    v.w = fmaxf(fmaf(v.w, s.w, t.w), 0.f);
    *p = v;
}

// ---------------- GEMM, K=128 ----------------
// C[M x NC] = act(A1@W1^T [+ A2@W2^T] + bias), W is [NC x 128] row-major.

template <int NC, bool DUAL, bool RELU>
__global__ __launch_bounds__(256) void gemm_k128(const float* A1, const float* __restrict__ W1g,
                                                 const float* A2, const float* __restrict__ W2g,
                                                 const float* __restrict__ bias, float* C, int M) {
    constexpr int BM = 64, BK = 32;
    constexpr int NG = NC / 64;   // column groups of 64
    constexpr int SA = 68;        // k-major A stride (floats), 16B-aligned rows
    constexpr int SW = NC + 4;    // 132 or 68
    __shared__ float As[BK * SA];
    __shared__ float Ws[BK * SW];
    const int tid = threadIdx.x;
    const int ty = tid >> 4;   // 0..15 -> rows ty*4..ty*4+3
    const int tx = tid & 15;   // 0..15 -> cols g*64 + tx*4..+3
    const int m0 = blockIdx.x * BM;

    float acc[4][NG][4];
#pragma unroll
    for (int i = 0; i < 4; i++)
#pragma unroll
        for (int g = 0; g < NG; g++)
#pragma unroll
            for (int j = 0; j < 4; j++) acc[i][g][j] = 0.f;

    const int npass = DUAL ? 2 : 1;
    for (int pass = 0; pass < npass; ++pass) {
        const float* A = (DUAL && pass) ? A2 : A1;
        const float* W = (DUAL && pass) ? W2g : W1g;
        for (int kc = 0; kc < 128; kc += BK) {
            // stage A tile [64 rows][32 k], transposed to k-major
#pragma unroll
            for (int i = 0; i < 2; i++) {
                int f = tid + i * 256;
                int row = f >> 3;
                int k4 = (f & 7) * 4;
                int gr = m0 + row;
                if (gr > M - 1) gr = M - 1;
                float4 v = *(const float4*)&A[(size_t)gr * 128 + kc + k4];
                As[(k4 + 0) * SA + row] = v.x;
                As[(k4 + 1) * SA + row] = v.y;
                As[(k4 + 2) * SA + row] = v.z;
                As[(k4 + 3) * SA + row] = v.w;
            }
            // stage W tile [NC][32 k], transposed to k-major
#pragma unroll
            for (int i = 0; i < NC / 32; i++) {
                int f = tid + i * 256;
                int n = f >> 3;
                int k4 = (f & 7) * 4;
                float4 v = *(const float4*)&W[(size_t)n * 128 + kc + k4];
                Ws[(k4 + 0) * SW + n] = v.x;
                Ws[(k4 + 1) * SW + n] = v.y;
                Ws[(k4 + 2) * SW + n] = v.z;
                Ws[(k4 + 3) * SW + n] = v.w;
            }
            __syncthreads();
#pragma unroll
            for (int k = 0; k < BK; k++) {
                const float4 a = *(const float4*)&As[k * SA + ty * 4];
                float av[4] = {a.x, a.y, a.z, a.w};
#pragma unroll
                for (int g = 0; g < NG; g++) {
                    const float4 w = *(const float4*)&Ws[k * SW + g * 64 + tx * 4];
                    float wv[4] = {w.x, w.y, w.z, w.w};
#pragma unroll
                    for (int i = 0; i < 4; i++)
#pragma unroll
                        for (int j = 0; j < 4; j++) acc[i][g][j] = fmaf(av[i], wv[j], acc[i][g][j]);
                }
            }
            __syncthreads();
        }
    }
    // epilogue
#pragma unroll
    for (int i = 0; i < 4; i++) {
        int m = m0 + ty * 4 + i;
        if (m >= M) break;
#pragma unroll
        for (int g = 0; g < NG; g++) {
            int n = g * 64 + tx * 4;
            float4 b = *(const float4*)&bias[n];
            float4 o;
            o.x = acc[i][g][0] + b.x;
            o.y = acc[i][g][1] + b.y;
            o.z = acc[i][g][2] + b.z;
            o.w = acc[i][g][3] + b.w;
            if (RELU) {
                o.x = fmaxf(o.x, 0.f); o.y = fmaxf(o.y, 0.f);
                o.z = fmaxf(o.z, 0.f); o.w = fmaxf(o.w, 0.f);
            }
            *(float4*)&C[(size_t)m * NC + n] = o;
        }
    }
}

// ---------------- launch ----------------

extern "C" void kernel_launch(void* const* d_in, const int* in_sizes, int n_in,
                              void* d_out, int out_size, void* d_ws, size_t ws_size,
                              hipStream_t stream) {
    const float* h   = (const float*)d_in[0];
    const float* W1  = (const float*)d_in[1];
    const float* b1  = (const float*)d_in[2];
    const float* g1  = (const float*)d_in[3];
    const float* bt1 = (const float*)d_in[4];
    const float* Ws1 = (const float*)d_in[5];
    const float* Wn1 = (const float*)d_in[6];
    const float* bs1 = (const float*)d_in[7];
    const float* W2  = (const float*)d_in[8];
    const float* b2  = (const float*)d_in[9];
    const float* g2  = (const float*)d_in[10];
    const float* bt2 = (const float*)d_in[11];
    const float* Ws2 = (const float*)d_in[12];
    const float* Wn2 = (const float*)d_in[13];
    const float* bs2 = (const float*)d_in[14];
    const float* W3  = (const float*)d_in[15];
    const float* b3  = (const float*)d_in[16];
    const int* src   = (const int*)d_in[17];
    const int* dst   = (const int*)d_in[18];
    float* out = (float*)d_out;

    const int N = NN, E = NE;
    char* ws = (char*)d_ws;
    size_t NB = (size_t)N * 128 * sizeof(float);
    float* bufA   = (float*)ws;                 // [N,128]
    float* bufB   = (float*)(ws + NB);          // [N,128] (agg/mean)
    float* deg    = (float*)(ws + 2 * NB);      // [N]
    float* invdeg = deg + N;                    // [N]
    float* stats  = invdeg + N;                 // [256]
    float* bnp    = stats + 256;                // [256]

    const int gm = (N + 63) / 64;
    const int ew = (E * 32 + 255) / 256;   // scatter grid
    const int nw = (N * 32 + 255) / 256;   // elementwise grid

    hipMemsetAsync(deg, 0, N * sizeof(float), stream);
    hipMemsetAsync(stats, 0, 256 * sizeof(float), stream);
    deg_kernel<<<(E + 255) / 256, 256, 0, stream>>>(dst, deg, E);
    invdeg_kernel<<<(N + 255) / 256, 256, 0, stream>>>(deg, invdeg, N);

    // dense1 + BN + ReLU
    gemm_k128<128, false, false><<<gm, 256, 0, stream>>>(h, W1, nullptr, nullptr, b1, bufA, N);
    colstats_kernel<<<1024, 256, 0, stream>>>(bufA, N, stats);
    bn_finalize_kernel<<<1, 128, 0, stream>>>(stats, g1, bt1, bnp, 1.0f / N);
    bn_relu_kernel<<<nw, 256, 0, stream>>>(bufA, bnp, N * 32);

    // SAGE 1 (in-place output into bufA is safe: row-m output depends only on row-m inputs)
    hipMemsetAsync(bufB, 0, NB, stream);
    scatter_kernel<<<ew, 256, 0, stream>>>(bufA, src, dst, bufB, E);
    meanscale_kernel<<<nw, 256, 0, stream>>>(bufB, invdeg, N * 32);
    gemm_k128<128, true, true><<<gm, 256, 0, stream>>>(bufA, Ws1, bufB, Wn1, bs1, bufA, N);

    // dense2 + BN + ReLU
    hipMemsetAsync(stats, 0, 256 * sizeof(float), stream);
    gemm_k128<128, false, false><<<gm, 256, 0, stream>>>(bufA, W2, nullptr, nullptr, b2, bufA, N);
    colstats_kernel<<<1024, 256, 0, stream>>>(bufA, N, stats);
    bn_finalize_kernel<<<1, 128, 0, stream>>>(stats, g2, bt2, bnp, 1.0f / N);
    bn_relu_kernel<<<nw, 256, 0, stream>>>(bufA, bnp, N * 32);

    // SAGE 2
    hipMemsetAsync(bufB, 0, NB, stream);
    scatter_kernel<<<ew, 256, 0, stream>>>(bufA, src, dst, bufB, E);
    meanscale_kernel<<<nw, 256, 0, stream>>>(bufB, invdeg, N * 32);
    gemm_k128<128, true, true><<<gm, 256, 0, stream>>>(bufA, Ws2, bufB, Wn2, bs2, bufA, N);

    // output layer
    gemm_k128<64, false, true><<<gm, 256, 0, stream>>>(bufA, W3, nullptr, nullptr, b3, out, N);
}

// Round 2
// 858.139 us; speedup vs baseline: 3.7194x; 3.7194x over previous
//
#include <hip/hip_runtime.h>
#include <hip/hip_bf16.h>
#include <cstddef>

// GNN: dense1+BN+ReLU -> SAGE(mean) -> dense2+BN+ReLU -> SAGE(mean) -> dense_out
// Round 1: replace atomic scatter aggregation (84% of runtime, atomic-bound)
// with on-device CSR build + wave-per-node gather-mean.
//   - CSR built per call (deterministic work): int-deg histogram -> 1-block
//     scan -> atomic-cursor fill. CSR lives in d_out scratch (final GEMM
//     overwrites d_out afterwards).
//   - gather_mean: 64-lane wave per node, float2/lane, sum in-neighbor rows
//     (X is 51.2 MB -> L3-resident), scale by 1/max(deg,1), single write.
//   - GEMM/BN unchanged from round 0 (fp32, VALU).

#define NN 100000
#define NE 800000

// ---------------- CSR build ----------------

__global__ __launch_bounds__(256) void ideg_kernel(const int* __restrict__ dst, int* ideg, int E) {
    int e = blockIdx.x * 256 + threadIdx.x;
    if (e < E) atomicAdd(&ideg[dst[e]], 1);
}

__global__ __launch_bounds__(1024) void scan_kernel(const int* __restrict__ ideg, int* row_ptr,
                                                    int* cursor, int n) {
    __shared__ int sdata[1024];
    int t = threadIdx.x;
    const int chunk = (n + 1023) / 1024;
    int lo = t * chunk, hi = min(n, lo + chunk);
    if (hi < lo) hi = lo;
    int s = 0;
    for (int i = lo; i < hi; i++) s += ideg[i];
    sdata[t] = s;
    __syncthreads();
    for (int off = 1; off < 1024; off <<= 1) {
        int v = (t >= off) ? sdata[t - off] : 0;
        __syncthreads();
        sdata[t] += v;
        __syncthreads();
    }
    int base = (t == 0) ? 0 : sdata[t - 1];
    for (int i = lo; i < hi; i++) {
        row_ptr[i] = base;
        cursor[i] = base;
        base += ideg[i];
    }
    if (t == 1023) row_ptr[n] = sdata[1023];
}

__global__ __launch_bounds__(256) void csr_fill_kernel(const int* __restrict__ src,
                                                       const int* __restrict__ dst,
                                                       int* cursor, int* csr_src, int E) {
    int e = blockIdx.x * 256 + threadIdx.x;
    if (e < E) {
        int pos = atomicAdd(&cursor[dst[e]], 1);
        csr_src[pos] = src[e];
    }
}

// ---------------- gather-mean aggregation ----------------
// one 64-lane wave per node; lane owns columns 2*lane, 2*lane+1

__global__ __launch_bounds__(256) void gather_mean_kernel(const float* __restrict__ X,
                                                          const int* __restrict__ row_ptr,
                                                          const int* __restrict__ csr_src,
                                                          float* __restrict__ out, int n) {
    int node = blockIdx.x * 4 + (threadIdx.x >> 6);
    if (node >= n) return;
    int lane = threadIdx.x & 63;
    int p = row_ptr[node], pe = row_ptr[node + 1];
    float inv = 1.0f / fmaxf((float)(pe - p), 1.0f);
    const float2* X2 = (const float2*)X;
    float ax = 0.f, ay = 0.f;
    for (; p + 1 < pe; p += 2) {
        int s0 = csr_src[p], s1 = csr_src[p + 1];
        float2 v0 = X2[(size_t)s0 * 64 + lane];
        float2 v1 = X2[(size_t)s1 * 64 + lane];
        ax += v0.x + v1.x;
        ay += v0.y + v1.y;
    }
    if (p < pe) {
        float2 v = X2[(size_t)csr_src[p] * 64 + lane];
        ax += v.x;
        ay += v.y;
    }
    float2 o;
    o.x = ax * inv;
    o.y = ay * inv;
    ((float2*)out)[(size_t)node * 64 + lane] = o;
}

// ---------------- batchnorm ----------------

__global__ __launch_bounds__(256) void colstats_kernel(const float* __restrict__ X, int M, float* stats) {
    __shared__ float sred[8][128];
    __shared__ float qred[8][128];
    int tid = threadIdx.x;
    int cg = (tid & 31) * 4;
    int rl = tid >> 5;
    float sx = 0, sy = 0, sz = 0, sw = 0, qx = 0, qy = 0, qz = 0, qw = 0;
    for (int r = blockIdx.x * 8 + rl; r < M; r += gridDim.x * 8) {
        float4 v = *(const float4*)&X[(size_t)r * 128 + cg];
        sx += v.x; sy += v.y; sz += v.z; sw += v.w;
        qx += v.x * v.x; qy += v.y * v.y; qz += v.z * v.z; qw += v.w * v.w;
    }
    sred[rl][cg + 0] = sx; sred[rl][cg + 1] = sy; sred[rl][cg + 2] = sz; sred[rl][cg + 3] = sw;
    qred[rl][cg + 0] = qx; qred[rl][cg + 1] = qy; qred[rl][cg + 2] = qz; qred[rl][cg + 3] = qw;
    __syncthreads();
    if (tid < 128) {
        float s = 0, q = 0;
#pragma unroll
        for (int r = 0; r < 8; r++) { s += sred[r][tid]; q += qred[r][tid]; }
        atomicAdd(&stats[tid], s);
        atomicAdd(&stats[128 + tid], q);
    }
}

__global__ void bn_finalize_kernel(const float* __restrict__ stats, const float* __restrict__ gamma,
                                   const float* __restrict__ beta, float* bnp, float invM) {
    int c = threadIdx.x;  // 128 threads
    float mean = stats[c] * invM;
    float var = stats[128 + c] * invM - mean * mean;
    float sc = gamma[c] * rsqrtf(var + 1e-5f);
    bnp[c] = sc;
    bnp[128 + c] = beta[c] - mean * sc;
}

__global__ __launch_bounds__(256) void bn_relu_kernel(float* X, const float* __restrict__ bnp, int n4) {
    int gid = blockIdx.x * 256 + threadIdx.x;
    if (gid >= n4) return;
    int c = (gid & 31) * 4;
    float4 s = *(const float4*)&bnp[c];
    float4 t = *(const float4*)&bnp[128 + c];
    float4* p = (float4*)X + gid;
    float4 v = *p;
    v.x = fmaxf(fmaf(v.x, s.x, t.x), 0.f);
    v.y = fmaxf(fmaf(v.y, s.y, t.y), 0.f);
    v.z = fmaxf(fmaf(v.z, s.z, t.z), 0.f);
    v.w = fmaxf(fmaf(v.w, s.w, t.w), 0.f);
    *p = v;
}

// ---------------- GEMM, K=128 ----------------
// C[M x NC] = act(A1@W1^T [+ A2@W2^T] + bias), W is [NC x 128] row-major.

template <int NC, bool DUAL, bool RELU>
__global__ __launch_bounds__(256) void gemm_k128(const float* A1, const float* __restrict__ W1g,
                                                 const float* A2, const float* __restrict__ W2g,
                                                 const float* __restrict__ bias, float* C, int M) {
    constexpr int BM = 64, BK = 32;
    constexpr int NG = NC / 64;
    constexpr int SA = 68;
    constexpr int SW = NC + 4;
    __shared__ float As[BK * SA];
    __shared__ float Ws[BK * SW];
    const int tid = threadIdx.x;
    const int ty = tid >> 4;
    const int tx = tid & 15;
    const int m0 = blockIdx.x * BM;

    float acc[4][NG][4];
#pragma unroll
    for (int i = 0; i < 4; i++)
#pragma unroll
        for (int g = 0; g < NG; g++)
#pragma unroll
            for (int j = 0; j < 4; j++) acc[i][g][j] = 0.f;

    const int npass = DUAL ? 2 : 1;
    for (int pass = 0; pass < npass; ++pass) {
        const float* A = (DUAL && pass) ? A2 : A1;
        const float* W = (DUAL && pass) ? W2g : W1g;
        for (int kc = 0; kc < 128; kc += BK) {
#pragma unroll
            for (int i = 0; i < 2; i++) {
                int f = tid + i * 256;
                int row = f >> 3;
                int k4 = (f & 7) * 4;
                int gr = m0 + row;
                if (gr > M - 1) gr = M - 1;
                float4 v = *(const float4*)&A[(size_t)gr * 128 + kc + k4];
                As[(k4 + 0) * SA + row] = v.x;
                As[(k4 + 1) * SA + row] = v.y;
                As[(k4 + 2) * SA + row] = v.z;
                As[(k4 + 3) * SA + row] = v.w;
            }
#pragma unroll
            for (int i = 0; i < NC / 32; i++) {
                int f = tid + i * 256;
                int n = f >> 3;
                int k4 = (f & 7) * 4;
                float4 v = *(const float4*)&W[(size_t)n * 128 + kc + k4];
                Ws[(k4 + 0) * SW + n] = v.x;
                Ws[(k4 + 1) * SW + n] = v.y;
                Ws[(k4 + 2) * SW + n] = v.z;
                Ws[(k4 + 3) * SW + n] = v.w;
            }
            __syncthreads();
#pragma unroll
            for (int k = 0; k < BK; k++) {
                const float4 a = *(const float4*)&As[k * SA + ty * 4];
                float av[4] = {a.x, a.y, a.z, a.w};
#pragma unroll
                for (int g = 0; g < NG; g++) {
                    const float4 w = *(const float4*)&Ws[k * SW + g * 64 + tx * 4];
                    float wv[4] = {w.x, w.y, w.z, w.w};
#pragma unroll
                    for (int i = 0; i < 4; i++)
#pragma unroll
                        for (int j = 0; j < 4; j++) acc[i][g][j] = fmaf(av[i], wv[j], acc[i][g][j]);
                }
            }
            __syncthreads();
        }
    }
#pragma unroll
    for (int i = 0; i < 4; i++) {
        int m = m0 + ty * 4 + i;
        if (m >= M) break;
#pragma unroll
        for (int g = 0; g < NG; g++) {
            int n = g * 64 + tx * 4;
            float4 b = *(const float4*)&bias[n];
            float4 o;
            o.x = acc[i][g][0] + b.x;
            o.y = acc[i][g][1] + b.y;
            o.z = acc[i][g][2] + b.z;
            o.w = acc[i][g][3] + b.w;
            if (RELU) {
                o.x = fmaxf(o.x, 0.f); o.y = fmaxf(o.y, 0.f);
                o.z = fmaxf(o.z, 0.f); o.w = fmaxf(o.w, 0.f);
            }
            *(float4*)&C[(size_t)m * NC + n] = o;
        }
    }
}

// ---------------- launch ----------------

extern "C" void kernel_launch(void* const* d_in, const int* in_sizes, int n_in,
                              void* d_out, int out_size, void* d_ws, size_t ws_size,
                              hipStream_t stream) {
    const float* h   = (const float*)d_in[0];
    const float* W1  = (const float*)d_in[1];
    const float* b1  = (const float*)d_in[2];
    const float* g1  = (const float*)d_in[3];
    const float* bt1 = (const float*)d_in[4];
    const float* Ws1 = (const float*)d_in[5];
    const float* Wn1 = (const float*)d_in[6];
    const float* bs1 = (const float*)d_in[7];
    const float* W2  = (const float*)d_in[8];
    const float* b2  = (const float*)d_in[9];
    const float* g2  = (const float*)d_in[10];
    const float* bt2 = (const float*)d_in[11];
    const float* Ws2 = (const float*)d_in[12];
    const float* Wn2 = (const float*)d_in[13];
    const float* bs2 = (const float*)d_in[14];
    const float* W3  = (const float*)d_in[15];
    const float* b3  = (const float*)d_in[16];
    const int* src   = (const int*)d_in[17];
    const int* dst   = (const int*)d_in[18];
    float* out = (float*)d_out;

    const int N = NN, E = NE;
    char* ws = (char*)d_ws;
    size_t NB = (size_t)N * 128 * sizeof(float);
    float* bufA  = (float*)ws;             // [N,128]
    float* bufB  = (float*)(ws + NB);      // [N,128] (mean agg)
    float* stats = (float*)(ws + 2 * NB);  // [256]
    float* bnp   = stats + 256;            // [256]

    // CSR scratch lives in d_out (25.6 MB); final GEMM overwrites it at the end.
    int* ideg    = (int*)d_out;      // [N]
    int* row_ptr = ideg + N;         // [N+1]
    int* cursor  = row_ptr + N + 1;  // [N]
    int* csr_src = cursor + N;       // [E]

    const int gm = (N + 63) / 64;
    const int nw = (N * 32 + 255) / 256;
    const int gg = (N + 3) / 4;

    // build CSR (per call; atomic fill order varies -> fp-noise only)
    hipMemsetAsync(ideg, 0, N * sizeof(int), stream);
    hipMemsetAsync(stats, 0, 256 * sizeof(float), stream);
    ideg_kernel<<<(E + 255) / 256, 256, 0, stream>>>(dst, ideg, E);
    scan_kernel<<<1, 1024, 0, stream>>>(ideg, row_ptr, cursor, N);
    csr_fill_kernel<<<(E + 255) / 256, 256, 0, stream>>>(src, dst, cursor, csr_src, E);

    // dense1 + BN + ReLU
    gemm_k128<128, false, false><<<gm, 256, 0, stream>>>(h, W1, nullptr, nullptr, b1, bufA, N);
    colstats_kernel<<<1024, 256, 0, stream>>>(bufA, N, stats);
    bn_finalize_kernel<<<1, 128, 0, stream>>>(stats, g1, bt1, bnp, 1.0f / N);
    bn_relu_kernel<<<nw, 256, 0, stream>>>(bufA, bnp, N * 32);

    // SAGE 1
    gather_mean_kernel<<<gg, 256, 0, stream>>>(bufA, row_ptr, csr_src, bufB, N);
    gemm_k128<128, true, true><<<gm, 256, 0, stream>>>(bufA, Ws1, bufB, Wn1, bs1, bufA, N);

    // dense2 + BN + ReLU
    hipMemsetAsync(stats, 0, 256 * sizeof(float), stream);
    gemm_k128<128, false, false><<<gm, 256, 0, stream>>>(bufA, W2, nullptr, nullptr, b2, bufA, N);
    colstats_kernel<<<1024, 256, 0, stream>>>(bufA, N, stats);
    bn_finalize_kernel<<<1, 128, 0, stream>>>(stats, g2, bt2, bnp, 1.0f / N);
    bn_relu_kernel<<<nw, 256, 0, stream>>>(bufA, bnp, N * 32);

    // SAGE 2
    gather_mean_kernel<<<gg, 256, 0, stream>>>(bufA, row_ptr, csr_src, bufB, N);
    gemm_k128<128, true, true><<<gm, 256, 0, stream>>>(bufA, Ws2, bufB, Wn2, bs2, bufA, N);

    // output layer
    gemm_k128<64, false, true><<<gm, 256, 0, stream>>>(bufA, W3, nullptr, nullptr, b3, out, N);
}

// Round 3
// 516.515 us; speedup vs baseline: 6.1794x; 1.6614x over previous
//
#include <hip/hip_runtime.h>
#include <hip/hip_bf16.h>
#include <cstddef>

// GNN: dense1+BN+ReLU -> SAGE(mean) -> dense2+BN+ReLU -> SAGE(mean) -> dense_out
// Round 2:
//   - parallel 3-phase CSR scan (was: 1-block scan, 228 us @ 0.15% occupancy)
//   - GEMM -> bf16 MFMA 16x16x32, A split hi+lo (2 passes) for fp32-A accuracy;
//     W single bf16 RTN. XOR-swizzled LDS tiles, ds_read_b128 fragments.

#define NN 100000
#define NE 800000

typedef __attribute__((ext_vector_type(8))) short short8;
typedef __attribute__((ext_vector_type(4))) float f32x4;

__device__ inline unsigned short f2bf(float f) {
    unsigned int u = __float_as_uint(f);
    u += 0x7fff + ((u >> 16) & 1);   // round-to-nearest-even
    return (unsigned short)(u >> 16);
}
__device__ inline float bf2f(unsigned short h) {
    return __uint_as_float(((unsigned int)h) << 16);
}

// ---------------- CSR build ----------------

__global__ __launch_bounds__(256) void ideg_kernel(const int* __restrict__ dst, int* ideg, int E) {
    int e = blockIdx.x * 256 + threadIdx.x;
    if (e < E) atomicAdd(&ideg[dst[e]], 1);
}

__global__ __launch_bounds__(256) void block_sums_kernel(const int* __restrict__ ideg, int* bsum, int n) {
    __shared__ int s[256];
    int tid = threadIdx.x;
    int i = blockIdx.x * 256 + tid;
    s[tid] = (i < n) ? ideg[i] : 0;
    __syncthreads();
#pragma unroll
    for (int off = 128; off > 0; off >>= 1) {
        if (tid < off) s[tid] += s[tid + off];
        __syncthreads();
    }
    if (tid == 0) bsum[blockIdx.x] = s[0];
}

__global__ __launch_bounds__(512) void scan_bsums_kernel(const int* __restrict__ bsum, int* boff, int nb) {
    __shared__ int s[512];
    int t = threadIdx.x;
    int v = (t < nb) ? bsum[t] : 0;
    s[t] = v;
    __syncthreads();
#pragma unroll
    for (int off = 1; off < 512; off <<= 1) {
        int u = (t >= off) ? s[t - off] : 0;
        __syncthreads();
        s[t] += u;
        __syncthreads();
    }
    if (t < nb) boff[t] = s[t] - v;  // exclusive
}

__global__ __launch_bounds__(256) void write_rowptr_kernel(const int* __restrict__ ideg,
                                                           const int* __restrict__ boff,
                                                           int* row_ptr, int* cursor, int n) {
    __shared__ int s[256];
    int tid = threadIdx.x;
    int i = blockIdx.x * 256 + tid;
    int v = (i < n) ? ideg[i] : 0;
    s[tid] = v;
    __syncthreads();
#pragma unroll
    for (int off = 1; off < 256; off <<= 1) {
        int u = (tid >= off) ? s[tid - off] : 0;
        __syncthreads();
        s[tid] += u;
        __syncthreads();
    }
    int excl = s[tid] - v + boff[blockIdx.x];
    if (i < n) {
        row_ptr[i] = excl;
        cursor[i] = excl;
        if (i == n - 1) row_ptr[n] = excl + v;
    }
}

__global__ __launch_bounds__(256) void csr_fill_kernel(const int* __restrict__ src,
                                                       const int* __restrict__ dst,
                                                       int* cursor, int* csr_src, int E) {
    int e = blockIdx.x * 256 + threadIdx.x;
    if (e < E) {
        int pos = atomicAdd(&cursor[dst[e]], 1);
        csr_src[pos] = src[e];
    }
}

// ---------------- gather-mean aggregation ----------------

__global__ __launch_bounds__(256) void gather_mean_kernel(const float* __restrict__ X,
                                                          const int* __restrict__ row_ptr,
                                                          const int* __restrict__ csr_src,
                                                          float* __restrict__ out, int n) {
    int node = blockIdx.x * 4 + (threadIdx.x >> 6);
    if (node >= n) return;
    int lane = threadIdx.x & 63;
    int p = row_ptr[node], pe = row_ptr[node + 1];
    float inv = 1.0f / fmaxf((float)(pe - p), 1.0f);
    const float2* X2 = (const float2*)X;
    float ax = 0.f, ay = 0.f;
    for (; p + 1 < pe; p += 2) {
        int s0 = csr_src[p], s1 = csr_src[p + 1];
        float2 v0 = X2[(size_t)s0 * 64 + lane];
        float2 v1 = X2[(size_t)s1 * 64 + lane];
        ax += v0.x + v1.x;
        ay += v0.y + v1.y;
    }
    if (p < pe) {
        float2 v = X2[(size_t)csr_src[p] * 64 + lane];
        ax += v.x;
        ay += v.y;
    }
    float2 o;
    o.x = ax * inv;
    o.y = ay * inv;
    ((float2*)out)[(size_t)node * 64 + lane] = o;
}

// ---------------- batchnorm ----------------

__global__ __launch_bounds__(256) void colstats_kernel(const float* __restrict__ X, int M, float* stats) {
    __shared__ float sred[8][128];
    __shared__ float qred[8][128];
    int tid = threadIdx.x;
    int cg = (tid & 31) * 4;
    int rl = tid >> 5;
    float sx = 0, sy = 0, sz = 0, sw = 0, qx = 0, qy = 0, qz = 0, qw = 0;
    for (int r = blockIdx.x * 8 + rl; r < M; r += gridDim.x * 8) {
        float4 v = *(const float4*)&X[(size_t)r * 128 + cg];
        sx += v.x; sy += v.y; sz += v.z; sw += v.w;
        qx += v.x * v.x; qy += v.y * v.y; qz += v.z * v.z; qw += v.w * v.w;
    }
    sred[rl][cg + 0] = sx; sred[rl][cg + 1] = sy; sred[rl][cg + 2] = sz; sred[rl][cg + 3] = sw;
    qred[rl][cg + 0] = qx; qred[rl][cg + 1] = qy; qred[rl][cg + 2] = qz; qred[rl][cg + 3] = qw;
    __syncthreads();
    if (tid < 128) {
        float s = 0, q = 0;
#pragma unroll
        for (int r = 0; r < 8; r++) { s += sred[r][tid]; q += qred[r][tid]; }
        atomicAdd(&stats[tid], s);
        atomicAdd(&stats[128 + tid], q);
    }
}

__global__ void bn_finalize_kernel(const float* __restrict__ stats, const float* __restrict__ gamma,
                                   const float* __restrict__ beta, float* bnp, float invM) {
    int c = threadIdx.x;  // 128 threads
    float mean = stats[c] * invM;
    float var = stats[128 + c] * invM - mean * mean;
    float sc = gamma[c] * rsqrtf(var + 1e-5f);
    bnp[c] = sc;
    bnp[128 + c] = beta[c] - mean * sc;
}

__global__ __launch_bounds__(256) void bn_relu_kernel(float* X, const float* __restrict__ bnp, int n4) {
    int gid = blockIdx.x * 256 + threadIdx.x;
    if (gid >= n4) return;
    int c = (gid & 31) * 4;
    float4 s = *(const float4*)&bnp[c];
    float4 t = *(const float4*)&bnp[128 + c];
    float4* p = (float4*)X + gid;
    float4 v = *p;
    v.x = fmaxf(fmaf(v.x, s.x, t.x), 0.f);
    v.y = fmaxf(fmaf(v.y, s.y, t.y), 0.f);
    v.z = fmaxf(fmaf(v.z, s.z, t.z), 0.f);
    v.w = fmaxf(fmaf(v.w, s.w, t.w), 0.f);
    *p = v;
}

// ---------------- MFMA GEMM, K=128 ----------------
// C[M x NC] = act(A1@W1^T [+ A2@W2^T] + bias); W [NC x 128] row-major.
// A split hi+lo bf16 (2 MFMA passes = fp32-A x bf16-W); K chunked by 64.
// LDS rows stride 128 B, XOR-swizzled: byteInRow ^= (row&7)<<4.

template <int NC, bool DUAL, bool RELU>
__global__ __launch_bounds__(256) void gemm_mfma(const float* A1, const float* __restrict__ W1g,
                                                 const float* A2, const float* __restrict__ W2g,
                                                 const float* __restrict__ bias, float* C, int M) {
    constexpr int NG = NC / 16;  // n-tiles per wave (8 or 4)
    __shared__ __align__(16) unsigned short As_h[64 * 64];
    __shared__ __align__(16) unsigned short As_l[64 * 64];
    __shared__ __align__(16) unsigned short Ws_s[NC * 64];

    const int tid = threadIdx.x;
    const int w = tid >> 6;
    const int lane = tid & 63;
    const int m0 = blockIdx.x * 64;

    f32x4 acc[NG];
#pragma unroll
    for (int g = 0; g < NG; g++) acc[g] = (f32x4){0.f, 0.f, 0.f, 0.f};

    const int ar = w * 16 + (lane & 15);       // A row in LDS for this lane
    const int g16 = (lane >> 4) * 16;          // 16B column slot within k-chunk

    const int npass = DUAL ? 2 : 1;
    for (int pass = 0; pass < npass; ++pass) {
        const float* A = (DUAL && pass) ? A2 : A1;
        const float* W = (DUAL && pass) ? W2g : W1g;
#pragma unroll
        for (int kc = 0; kc < 128; kc += 64) {
            // ---- stage A chunk: 64 rows x 64 k fp32 -> hi/lo bf16 ----
#pragma unroll
            for (int i = 0; i < 4; i++) {
                int f = tid + i * 256;           // 0..1023
                int row = f >> 4;
                int k4 = (f & 15) * 4;
                int gr = m0 + row;
                if (gr > M - 1) gr = M - 1;
                float4 v = *(const float4*)&A[(size_t)gr * 128 + kc + k4];
                unsigned short h0 = f2bf(v.x), h1 = f2bf(v.y), h2 = f2bf(v.z), h3 = f2bf(v.w);
                short4 hv = {(short)h0, (short)h1, (short)h2, (short)h3};
                short4 lv = {(short)f2bf(v.x - bf2f(h0)), (short)f2bf(v.y - bf2f(h1)),
                             (short)f2bf(v.z - bf2f(h2)), (short)f2bf(v.w - bf2f(h3))};
                int off = row * 128 + ((k4 * 2) ^ ((row & 7) << 4));
                *(short4*)((char*)As_h + off) = hv;
                *(short4*)((char*)As_l + off) = lv;
            }
            // ---- stage W chunk: NC rows x 64 k fp32 -> bf16 ----
#pragma unroll
            for (int i = 0; i < NC / 16; i++) {
                int f = tid + i * 256;           // 0..NC*16-1
                int row = f >> 4;
                int k4 = (f & 15) * 4;
                float4 v = *(const float4*)&W[(size_t)row * 128 + kc + k4];
                short4 hv = {(short)f2bf(v.x), (short)f2bf(v.y), (short)f2bf(v.z), (short)f2bf(v.w)};
                int off = row * 128 + ((k4 * 2) ^ ((row & 7) << 4));
                *(short4*)((char*)Ws_s + off) = hv;
            }
            __syncthreads();
            // ---- compute: 2 k-steps of 32 ----
#pragma unroll
            for (int ks = 0; ks < 2; ks++) {
                int aoff = ar * 128 + ((ks * 64 + g16) ^ ((ar & 7) << 4));
                short8 ah = *(const short8*)((const char*)As_h + aoff);
                short8 al = *(const short8*)((const char*)As_l + aoff);
#pragma unroll
                for (int g = 0; g < NG; g++) {
                    int br = g * 16 + (lane & 15);
                    int boff = br * 128 + ((ks * 64 + g16) ^ ((br & 7) << 4));
                    short8 bh = *(const short8*)((const char*)Ws_s + boff);
                    acc[g] = __builtin_amdgcn_mfma_f32_16x16x32_bf16(ah, bh, acc[g], 0, 0, 0);
                    acc[g] = __builtin_amdgcn_mfma_f32_16x16x32_bf16(al, bh, acc[g], 0, 0, 0);
                }
            }
            __syncthreads();
        }
    }
    // ---- epilogue: row=(lane>>4)*4+reg, col=g*16+(lane&15) ----
    const int rbase = m0 + w * 16 + (lane >> 4) * 4;
    const int cbase = lane & 15;
#pragma unroll
    for (int g = 0; g < NG; g++) {
        int col = g * 16 + cbase;
        float b = bias[col];
#pragma unroll
        for (int r = 0; r < 4; r++) {
            int row = rbase + r;
            if (row < M) {
                float o = acc[g][r] + b;
                if (RELU) o = fmaxf(o, 0.f);
                C[(size_t)row * NC + col] = o;
            }
        }
    }
}

// ---------------- launch ----------------

extern "C" void kernel_launch(void* const* d_in, const int* in_sizes, int n_in,
                              void* d_out, int out_size, void* d_ws, size_t ws_size,
                              hipStream_t stream) {
    const float* h   = (const float*)d_in[0];
    const float* W1  = (const float*)d_in[1];
    const float* b1  = (const float*)d_in[2];
    const float* g1  = (const float*)d_in[3];
    const float* bt1 = (const float*)d_in[4];
    const float* Ws1 = (const float*)d_in[5];
    const float* Wn1 = (const float*)d_in[6];
    const float* bs1 = (const float*)d_in[7];
    const float* W2  = (const float*)d_in[8];
    const float* b2  = (const float*)d_in[9];
    const float* g2  = (const float*)d_in[10];
    const float* bt2 = (const float*)d_in[11];
    const float* Ws2 = (const float*)d_in[12];
    const float* Wn2 = (const float*)d_in[13];
    const float* bs2 = (const float*)d_in[14];
    const float* W3  = (const float*)d_in[15];
    const float* b3  = (const float*)d_in[16];
    const int* src   = (const int*)d_in[17];
    const int* dst   = (const int*)d_in[18];
    float* out = (float*)d_out;

    const int N = NN, E = NE;
    char* ws = (char*)d_ws;
    size_t NB = (size_t)N * 128 * sizeof(float);
    float* bufA  = (float*)ws;             // [N,128]
    float* bufB  = (float*)(ws + NB);      // [N,128] (mean agg)
    float* stats = (float*)(ws + 2 * NB);  // [256]
    float* bnp   = stats + 256;            // [256]
    int*   bsum  = (int*)(bnp + 256);      // [512]
    int*   boff  = bsum + 512;             // [512]

    // CSR scratch lives in d_out (25.6 MB); final GEMM overwrites it at the end.
    int* ideg    = (int*)d_out;      // [N]
    int* row_ptr = ideg + N;         // [N+1]
    int* cursor  = row_ptr + N + 1;  // [N]
    int* csr_src = cursor + N;       // [E]

    const int gm = (N + 63) / 64;
    const int nw = (N * 32 + 255) / 256;
    const int gg = (N + 3) / 4;
    const int nb = (N + 255) / 256;  // 391 scan blocks

    // build CSR (per call; atomic fill order varies -> fp-noise only)
    hipMemsetAsync(ideg, 0, N * sizeof(int), stream);
    hipMemsetAsync(stats, 0, 256 * sizeof(float), stream);
    ideg_kernel<<<(E + 255) / 256, 256, 0, stream>>>(dst, ideg, E);
    block_sums_kernel<<<nb, 256, 0, stream>>>(ideg, bsum, N);
    scan_bsums_kernel<<<1, 512, 0, stream>>>(bsum, boff, nb);
    write_rowptr_kernel<<<nb, 256, 0, stream>>>(ideg, boff, row_ptr, cursor, N);
    csr_fill_kernel<<<(E + 255) / 256, 256, 0, stream>>>(src, dst, cursor, csr_src, E);

    // dense1 + BN + ReLU
    gemm_mfma<128, false, false><<<gm, 256, 0, stream>>>(h, W1, nullptr, nullptr, b1, bufA, N);
    colstats_kernel<<<1024, 256, 0, stream>>>(bufA, N, stats);
    bn_finalize_kernel<<<1, 128, 0, stream>>>(stats, g1, bt1, bnp, 1.0f / N);
    bn_relu_kernel<<<nw, 256, 0, stream>>>(bufA, bnp, N * 32);

    // SAGE 1
    gather_mean_kernel<<<gg, 256, 0, stream>>>(bufA, row_ptr, csr_src, bufB, N);
    gemm_mfma<128, true, true><<<gm, 256, 0, stream>>>(bufA, Ws1, bufB, Wn1, bs1, bufA, N);

    // dense2 + BN + ReLU
    hipMemsetAsync(stats, 0, 256 * sizeof(float), stream);
    gemm_mfma<128, false, false><<<gm, 256, 0, stream>>>(bufA, W2, nullptr, nullptr, b2, bufA, N);
    colstats_kernel<<<1024, 256, 0, stream>>>(bufA, N, stats);
    bn_finalize_kernel<<<1, 128, 0, stream>>>(stats, g2, bt2, bnp, 1.0f / N);
    bn_relu_kernel<<<nw, 256, 0, stream>>>(bufA, bnp, N * 32);

    // SAGE 2
    gather_mean_kernel<<<gg, 256, 0, stream>>>(bufA, row_ptr, csr_src, bufB, N);
    gemm_mfma<128, true, true><<<gm, 256, 0, stream>>>(bufA, Ws2, bufB, Wn2, bs2, bufA, N);

    // output layer
    gemm_mfma<64, false, true><<<gm, 256, 0, stream>>>(bufA, W3, nullptr, nullptr, b3, out, N);
}

// Round 4
// 392.225 us; speedup vs baseline: 8.1376x; 1.3169x over previous
//
#include <hip/hip_runtime.h>
#include <hip/hip_bf16.h>
#include <cstddef>

// GNN: dense1+BN+ReLU -> SAGE(mean) -> dense2+BN+ReLU -> SAGE(mean) -> dense_out
// Round 4: all activations/weights single bf16 (uses accuracy headroom).
//   - pre-convert h and all 7 weight mats to bf16 once per call
//   - GEMM: single-shot K=128, global_load_lds(16B) staging with pre-swizzled
//     global source (slot ^= row&7), ds_read_b128 fragments, 1 barrier,
//     BN column stats fused into epilogue (fp32 acc, exact); bias skipped for
//     BN'd layers (cancels in BN).
//   - gather-mean reads bf16 rows (half the bytes of round 3).

#define NN 100000
#define NE 800000

typedef __attribute__((ext_vector_type(8))) short short8;
typedef __attribute__((ext_vector_type(4))) float f32x4;

__device__ inline unsigned short f2bf(float f) {
    unsigned int u = __float_as_uint(f);
    u += 0x7fff + ((u >> 16) & 1);   // round-to-nearest-even
    return (unsigned short)(u >> 16);
}

#define GLOAD16(gp, lp)                                                              \
    __builtin_amdgcn_global_load_lds((const __attribute__((address_space(1))) unsigned int*)(gp), \
                                     (__attribute__((address_space(3))) unsigned int*)(lp), 16, 0, 0)

// ---------------- conversions ----------------

__global__ __launch_bounds__(256) void cvt_bf16_kernel(const float* __restrict__ in,
                                                       unsigned short* __restrict__ out, int n4) {
    int gid = blockIdx.x * 256 + threadIdx.x;
    if (gid >= n4) return;
    float4 v = ((const float4*)in)[gid];
    ushort4 o = {f2bf(v.x), f2bf(v.y), f2bf(v.z), f2bf(v.w)};
    *(ushort4*)&out[(size_t)gid * 4] = o;
}

// all 7 weight matrices -> one bf16 buffer (offsets in elements):
// W1@0 Ws1@16384 Wn1@32768 W2@49152 Ws2@65536 Wn2@81920 W3@98304 (+8192)
__global__ __launch_bounds__(256) void wcvt_kernel(const float* W1, const float* Ws1, const float* Wn1,
                                                   const float* W2, const float* Ws2, const float* Wn2,
                                                   const float* W3, unsigned short* out) {
    int g4 = blockIdx.x * 256 + threadIdx.x;  // float4 index; total 106496/4 = 26624
    if (g4 >= 26624) return;
    int e = g4 * 4;
    const float* src;
    int off;
    if (e < 98304) {
        int m = e >> 14;
        off = e & 16383;
        src = (m == 0) ? W1 : (m == 1) ? Ws1 : (m == 2) ? Wn1 : (m == 3) ? W2 : (m == 4) ? Ws2 : Wn2;
    } else {
        src = W3;
        off = e - 98304;
    }
    float4 v = *(const float4*)&src[off];
    ushort4 o = {f2bf(v.x), f2bf(v.y), f2bf(v.z), f2bf(v.w)};
    *(ushort4*)&out[e] = o;
}

// ---------------- CSR build ----------------

__global__ __launch_bounds__(256) void ideg_kernel(const int* __restrict__ dst, int* ideg, int E) {
    int e = blockIdx.x * 256 + threadIdx.x;
    if (e < E) atomicAdd(&ideg[dst[e]], 1);
}

__global__ __launch_bounds__(256) void block_sums_kernel(const int* __restrict__ ideg, int* bsum, int n) {
    __shared__ int s[256];
    int tid = threadIdx.x;
    int i = blockIdx.x * 256 + tid;
    s[tid] = (i < n) ? ideg[i] : 0;
    __syncthreads();
#pragma unroll
    for (int off = 128; off > 0; off >>= 1) {
        if (tid < off) s[tid] += s[tid + off];
        __syncthreads();
    }
    if (tid == 0) bsum[blockIdx.x] = s[0];
}

__global__ __launch_bounds__(512) void scan_bsums_kernel(const int* __restrict__ bsum, int* boff, int nb) {
    __shared__ int s[512];
    int t = threadIdx.x;
    int v = (t < nb) ? bsum[t] : 0;
    s[t] = v;
    __syncthreads();
#pragma unroll
    for (int off = 1; off < 512; off <<= 1) {
        int u = (t >= off) ? s[t - off] : 0;
        __syncthreads();
        s[t] += u;
        __syncthreads();
    }
    if (t < nb) boff[t] = s[t] - v;  // exclusive
}

__global__ __launch_bounds__(256) void write_rowptr_kernel(const int* __restrict__ ideg,
                                                           const int* __restrict__ boff,
                                                           int* row_ptr, int* cursor, int n) {
    __shared__ int s[256];
    int tid = threadIdx.x;
    int i = blockIdx.x * 256 + tid;
    int v = (i < n) ? ideg[i] : 0;
    s[tid] = v;
    __syncthreads();
#pragma unroll
    for (int off = 1; off < 256; off <<= 1) {
        int u = (tid >= off) ? s[tid - off] : 0;
        __syncthreads();
        s[tid] += u;
        __syncthreads();
    }
    int excl = s[tid] - v + boff[blockIdx.x];
    if (i < n) {
        row_ptr[i] = excl;
        cursor[i] = excl;
        if (i == n - 1) row_ptr[n] = excl + v;
    }
}

__global__ __launch_bounds__(256) void csr_fill_kernel(const int* __restrict__ src,
                                                       const int* __restrict__ dst,
                                                       int* cursor, int* csr_src, int E) {
    int e = blockIdx.x * 256 + threadIdx.x;
    if (e < E) {
        int pos = atomicAdd(&cursor[dst[e]], 1);
        csr_src[pos] = src[e];
    }
}

// ---------------- gather-mean (bf16 rows) ----------------
// one 64-lane wave per node; lane owns cols 2*lane, 2*lane+1 (one uint)

__global__ __launch_bounds__(256) void gather_mean_kernel(const unsigned int* __restrict__ X32,
                                                          const int* __restrict__ row_ptr,
                                                          const int* __restrict__ csr_src,
                                                          unsigned int* __restrict__ Mout, int n) {
    int node = blockIdx.x * 4 + (threadIdx.x >> 6);
    if (node >= n) return;
    int lane = threadIdx.x & 63;
    int p = row_ptr[node], pe = row_ptr[node + 1];
    float inv = 1.0f / fmaxf((float)(pe - p), 1.0f);
    float ax = 0.f, ay = 0.f;
    for (; p + 1 < pe; p += 2) {
        unsigned u0 = X32[(size_t)csr_src[p] * 64 + lane];
        unsigned u1 = X32[(size_t)csr_src[p + 1] * 64 + lane];
        ax += __uint_as_float(u0 << 16) + __uint_as_float(u1 << 16);
        ay += __uint_as_float(u0 & 0xffff0000u) + __uint_as_float(u1 & 0xffff0000u);
    }
    if (p < pe) {
        unsigned u = X32[(size_t)csr_src[p] * 64 + lane];
        ax += __uint_as_float(u << 16);
        ay += __uint_as_float(u & 0xffff0000u);
    }
    unsigned o = (unsigned)f2bf(ax * inv) | ((unsigned)f2bf(ay * inv) << 16);
    Mout[(size_t)node * 64 + lane] = o;
}

// ---------------- batchnorm ----------------

__global__ void bn_finalize_kernel(const float* __restrict__ stats, const float* __restrict__ gamma,
                                   const float* __restrict__ beta, float* bnp, float invM) {
    int c = threadIdx.x;  // 128 threads
    float mean = stats[c] * invM;
    float var = stats[128 + c] * invM - mean * mean;
    float sc = gamma[c] * rsqrtf(var + 1e-5f);
    bnp[c] = sc;
    bnp[128 + c] = beta[c] - mean * sc;
}

// Y fp32 -> X bf16 with scale/shift + relu
__global__ __launch_bounds__(256) void bn_relu_kernel(const float* __restrict__ Y,
                                                      const float* __restrict__ bnp,
                                                      unsigned short* __restrict__ X, int n4) {
    int gid = blockIdx.x * 256 + threadIdx.x;
    if (gid >= n4) return;
    int c = (gid & 31) * 4;
    float4 s = *(const float4*)&bnp[c];
    float4 t = *(const float4*)&bnp[128 + c];
    float4 v = ((const float4*)Y)[gid];
    v.x = fmaxf(fmaf(v.x, s.x, t.x), 0.f);
    v.y = fmaxf(fmaf(v.y, s.y, t.y), 0.f);
    v.z = fmaxf(fmaf(v.z, s.z, t.z), 0.f);
    v.w = fmaxf(fmaf(v.w, s.w, t.w), 0.f);
    ushort4 o = {f2bf(v.x), f2bf(v.y), f2bf(v.z), f2bf(v.w)};
    *(ushort4*)&X[(size_t)gid * 4] = o;
}

// ---------------- MFMA GEMM, K=128, bf16 in ----------------
// C[M x NC] = act(A1@W1^T [+ A2@W2^T] [+ bias]); A,W bf16 row-major [.,128].
// BM=128, 4 waves; wave w: rows w*32..+32 (2 m-tiles), all NC cols.
// LDS: A 32KB @0, W NC*256B after. Staged via global_load_lds with
// pre-swizzled source: global slot read for LDS slot s of row r is s^(r&7).
// ds_read: slot = (ks*4 + (lane>>4)) ^ (row&7).

template <int NC, bool DUAL, bool RELU, bool STATS, bool OUTBF, bool BIAS>
__global__ __launch_bounds__(256) void gemm_bf16(const unsigned short* A1, const unsigned short* W1b,
                                                 const unsigned short* A2, const unsigned short* W2b,
                                                 const float* __restrict__ bias, void* Cout,
                                                 float* stats, int M) {
    constexpr int NG = NC / 16;
    constexpr int ABYTES = 128 * 256;
    __shared__ __align__(16) char smem[ABYTES + NC * 256];

    const int tid = threadIdx.x;
    const int w = tid >> 6, lane = tid & 63;
    const int m0 = blockIdx.x * 128;

    f32x4 acc[2][NG];
#pragma unroll
    for (int mt = 0; mt < 2; mt++)
#pragma unroll
        for (int g = 0; g < NG; g++) acc[mt][g] = (f32x4){0.f, 0.f, 0.f, 0.f};

    const int npass = DUAL ? 2 : 1;
    for (int pass = 0; pass < npass; ++pass) {
        const unsigned short* A = (DUAL && pass) ? A2 : A1;
        const unsigned short* W = (DUAL && pass) ? W2b : W1b;
        // stage A: 32 issues of 1KB (4 rows each); wave w takes 8
#pragma unroll
        for (int i = 0; i < 8; i++) {
            int iss = w * 8 + i;
            int row = iss * 4 + (lane >> 4);
            int gr = m0 + row;
            if (gr > M - 1) gr = M - 1;
            int slot = (lane & 15) ^ (row & 7);
            GLOAD16((const char*)A + (size_t)gr * 256 + (slot << 4), smem + iss * 1024);
        }
        // stage W: NC/4 issues; wave w takes NC/16
#pragma unroll
        for (int i = 0; i < NC / 16; i++) {
            int iss = w * (NC / 16) + i;
            int row = iss * 4 + (lane >> 4);
            int slot = (lane & 15) ^ (row & 7);
            GLOAD16((const char*)W + (size_t)row * 256 + (slot << 4), smem + ABYTES + iss * 1024);
        }
        __syncthreads();
#pragma unroll
        for (int ks = 0; ks < 4; ks++) {
            int ar0 = w * 32 + (lane & 15);
            int ar1 = ar0 + 16;
            short8 a0 = *(const short8*)(smem + ar0 * 256 + ((((ks * 4 + (lane >> 4))) ^ (ar0 & 7)) << 4));
            short8 a1 = *(const short8*)(smem + ar1 * 256 + ((((ks * 4 + (lane >> 4))) ^ (ar1 & 7)) << 4));
#pragma unroll
            for (int g = 0; g < NG; g++) {
                int wr = g * 16 + (lane & 15);
                short8 bw = *(const short8*)(smem + ABYTES + wr * 256 +
                                             ((((ks * 4 + (lane >> 4))) ^ (wr & 7)) << 4));
                acc[0][g] = __builtin_amdgcn_mfma_f32_16x16x32_bf16(a0, bw, acc[0][g], 0, 0, 0);
                acc[1][g] = __builtin_amdgcn_mfma_f32_16x16x32_bf16(a1, bw, acc[1][g], 0, 0, 0);
            }
        }
        if (DUAL && pass + 1 < npass) __syncthreads();
    }
    // epilogue: row = m0 + w*32 + mt*16 + (lane>>4)*4 + r, col = g*16 + (lane&15)
    const int r0 = (lane >> 4) * 4;
    const int cl = lane & 15;
#pragma unroll
    for (int mt = 0; mt < 2; mt++) {
        int rowb = m0 + w * 32 + mt * 16 + r0;
#pragma unroll
        for (int g = 0; g < NG; g++) {
            int col = g * 16 + cl;
            float b = BIAS ? bias[col] : 0.f;
#pragma unroll
            for (int r = 0; r < 4; r++) {
                int row = rowb + r;
                if (row < M) {
                    float o = acc[mt][g][r] + b;
                    if (RELU) o = fmaxf(o, 0.f);
                    if (OUTBF)
                        ((unsigned short*)Cout)[(size_t)row * NC + col] = f2bf(o);
                    else
                        ((float*)Cout)[(size_t)row * NC + col] = o;
                }
            }
        }
    }
    if (STATS) {
        __syncthreads();  // all waves done with LDS tiles -> reuse as reduce buffer
        float2* part = (float2*)smem;  // [16][128] float2 = 16KB
        const int widx = w * 4 + (lane >> 4);
#pragma unroll
        for (int g = 0; g < NG; g++) {
            float s = 0.f, q = 0.f;
#pragma unroll
            for (int mt = 0; mt < 2; mt++) {
                int rowb = m0 + w * 32 + mt * 16 + r0;
#pragma unroll
                for (int r = 0; r < 4; r++)
                    if (rowb + r < M) {
                        float v = acc[mt][g][r];
                        s += v;
                        q += v * v;
                    }
            }
            part[widx * 128 + g * 16 + cl] = make_float2(s, q);
        }
        __syncthreads();
        if (tid < 128) {
            float s = 0.f, q = 0.f;
#pragma unroll
            for (int i = 0; i < 16; i++) {
                float2 v = part[i * 128 + tid];
                s += v.x;
                q += v.y;
            }
            atomicAdd(&stats[tid], s);
            atomicAdd(&stats[128 + tid], q);
        }
    }
}

// ---------------- launch ----------------

extern "C" void kernel_launch(void* const* d_in, const int* in_sizes, int n_in,
                              void* d_out, int out_size, void* d_ws, size_t ws_size,
                              hipStream_t stream) {
    const float* h   = (const float*)d_in[0];
    const float* W1  = (const float*)d_in[1];
    const float* g1  = (const float*)d_in[3];
    const float* bt1 = (const float*)d_in[4];
    const float* Ws1 = (const float*)d_in[5];
    const float* Wn1 = (const float*)d_in[6];
    const float* bs1 = (const float*)d_in[7];
    const float* W2  = (const float*)d_in[8];
    const float* g2  = (const float*)d_in[10];
    const float* bt2 = (const float*)d_in[11];
    const float* Ws2 = (const float*)d_in[12];
    const float* Wn2 = (const float*)d_in[13];
    const float* bs2 = (const float*)d_in[14];
    const float* W3  = (const float*)d_in[15];
    const float* b3  = (const float*)d_in[16];
    const int* src   = (const int*)d_in[17];
    const int* dst   = (const int*)d_in[18];
    float* out = (float*)d_out;

    const int N = NN, E = NE;
    char* ws = (char*)d_ws;
    unsigned short* hb = (unsigned short*)ws;               // [N,128] bf16, 25.6MB
    unsigned short* Xb = (unsigned short*)(ws + 25600000);  // [N,128] bf16, 25.6MB
    float* Y = (float*)(ws + 51200000);                     // [N,128] fp32, 51.2MB
    unsigned int* Mb = (unsigned int*)Y;                    // alias: M bf16 lives in Y space
    char* tail = ws + 102400000;
    float* stats = (float*)tail;        // [256]
    float* bnp = stats + 256;           // [256]
    int* bsum = (int*)(bnp + 256);      // [512]
    int* boff = bsum + 512;             // [512]
    unsigned short* Wb = (unsigned short*)(boff + 512);  // 106496 bf16
    const unsigned short* Wb1  = Wb;
    const unsigned short* Wbs1 = Wb + 16384;
    const unsigned short* Wbn1 = Wb + 32768;
    const unsigned short* Wb2  = Wb + 49152;
    const unsigned short* Wbs2 = Wb + 65536;
    const unsigned short* Wbn2 = Wb + 81920;
    const unsigned short* Wb3  = Wb + 98304;

    // CSR scratch in d_out (overwritten by final GEMM)
    int* ideg    = (int*)d_out;      // [N]
    int* row_ptr = ideg + N;         // [N+1]
    int* cursor  = row_ptr + N + 1;  // [N]
    int* csr_src = cursor + N;       // [E]

    const int gm = (N + 127) / 128;       // 782 GEMM blocks
    const int nw = (N * 32 + 255) / 256;  // elementwise float4 grid
    const int gg = (N + 3) / 4;           // gather
    const int nb = (N + 255) / 256;       // 391 scan blocks

    // conversions + CSR build
    hipMemsetAsync(ideg, 0, N * sizeof(int), stream);
    hipMemsetAsync(stats, 0, 256 * sizeof(float), stream);
    wcvt_kernel<<<104, 256, 0, stream>>>(W1, Ws1, Wn1, W2, Ws2, Wn2, W3, Wb);
    cvt_bf16_kernel<<<nw, 256, 0, stream>>>(h, hb, N * 32);
    ideg_kernel<<<(E + 255) / 256, 256, 0, stream>>>(dst, ideg, E);
    block_sums_kernel<<<nb, 256, 0, stream>>>(ideg, bsum, N);
    scan_bsums_kernel<<<1, 512, 0, stream>>>(bsum, boff, nb);
    write_rowptr_kernel<<<nb, 256, 0, stream>>>(ideg, boff, row_ptr, cursor, N);
    csr_fill_kernel<<<(E + 255) / 256, 256, 0, stream>>>(src, dst, cursor, csr_src, E);

    // dense1 (stats fused, bias cancels in BN) + BN + ReLU
    gemm_bf16<128, false, false, true, false, false>
        <<<gm, 256, 0, stream>>>(hb, Wb1, nullptr, nullptr, nullptr, Y, stats, N);
    bn_finalize_kernel<<<1, 128, 0, stream>>>(stats, g1, bt1, bnp, 1.0f / N);
    bn_relu_kernel<<<nw, 256, 0, stream>>>(Y, bnp, Xb, N * 32);

    // SAGE 1 (M aliases Y: Y dead after bn_relu)
    gather_mean_kernel<<<gg, 256, 0, stream>>>((const unsigned int*)Xb, row_ptr, csr_src, Mb, N);
    gemm_bf16<128, true, true, false, true, true>
        <<<gm, 256, 0, stream>>>(Xb, Wbs1, (const unsigned short*)Mb, Wbn1, bs1, Xb, nullptr, N);

    // dense2 + BN + ReLU
    hipMemsetAsync(stats, 0, 256 * sizeof(float), stream);
    gemm_bf16<128, false, false, true, false, false>
        <<<gm, 256, 0, stream>>>(Xb, Wb2, nullptr, nullptr, nullptr, Y, stats, N);
    bn_finalize_kernel<<<1, 128, 0, stream>>>(stats, g2, bt2, bnp, 1.0f / N);
    bn_relu_kernel<<<nw, 256, 0, stream>>>(Y, bnp, Xb, N * 32);

    // SAGE 2
    gather_mean_kernel<<<gg, 256, 0, stream>>>((const unsigned int*)Xb, row_ptr, csr_src, Mb, N);
    gemm_bf16<128, true, true, false, true, true>
        <<<gm, 256, 0, stream>>>(Xb, Wbs2, (const unsigned short*)Mb, Wbn2, bs2, Xb, nullptr, N);

    // output layer
    gemm_bf16<64, false, true, false, false, true>
        <<<gm, 256, 0, stream>>>(Xb, Wb3, nullptr, nullptr, b3, out, nullptr, N);
}